// Round 2
// baseline (726.422 us; speedup 1.0000x reference)
//
#include <hip/hip_runtime.h>
#include <hip/hip_bf16.h>

namespace {

constexpr int B = 128, N = 2048, E = 32768;
constexpr int LOG2N = 11, LOG2E = 15;

// ws layout (bytes)
constexpr size_t OFF_H0     = 0;                     // B*N float4  = 4 MB
constexpr size_t OFF_H1     = 4u  * 1024 * 1024;     // B*N float4  = 4 MB
constexpr size_t OFF_SORTED = 8u  * 1024 * 1024;     // B*E int     = 16 MB
constexpr size_t OFF_CNT    = 24u * 1024 * 1024;     // B*N int     = 1 MB
constexpr size_t OFF_CUR    = 25u * 1024 * 1024;     // B*N int     = 1 MB
constexpr size_t OFF_RP     = 26u * 1024 * 1024;     // B*(N+1) int

__global__ void hist_kernel(const int* __restrict__ edge_index, int* __restrict__ cnt) {
  int i = blockIdx.x * blockDim.x + threadIdx.x;  // B*E exact
  int b = i >> LOG2E, e = i & (E - 1);
  int dst = edge_index[((b * 2 + 1) << LOG2E) + e];
  atomicAdd(&cnt[(b << LOG2N) + dst], 1);
}

// per-batch exclusive scan of cnt -> row_ptr and cursor
__global__ void scan_kernel(const int* __restrict__ cnt, int* __restrict__ row_ptr,
                            int* __restrict__ cursor) {
  __shared__ int lds[N];
  __shared__ int partial[256];
  int b = blockIdx.x, t = threadIdx.x;
  for (int j = t; j < N; j += 256) lds[j] = cnt[(b << LOG2N) + j];
  __syncthreads();
  int base = t * 8, sum = 0, local[8];
#pragma unroll
  for (int j = 0; j < 8; j++) { local[j] = lds[base + j]; sum += local[j]; }
  partial[t] = sum;
  __syncthreads();
  for (int d = 1; d < 256; d <<= 1) {
    int v = (t >= d) ? partial[t - d] : 0;
    __syncthreads();
    partial[t] += v;
    __syncthreads();
  }
  int run = partial[t] - sum;  // exclusive chunk offset
#pragma unroll
  for (int j = 0; j < 8; j++) {
    row_ptr[b * (N + 1) + base + j] = run;
    cursor[(b << LOG2N) + base + j] = run;
    run += local[j];
  }
  if (t == 255) row_ptr[b * (N + 1) + N] = run;  // == E
}

__global__ void scatter_kernel(const int* __restrict__ edge_index, int* __restrict__ cursor,
                               int* __restrict__ sorted) {
  int i = blockIdx.x * blockDim.x + threadIdx.x;  // B*E exact
  int b = i >> LOG2E, e = i & (E - 1);
  int src = edge_index[((b * 2 + 0) << LOG2E) + e];
  int dst = edge_index[((b * 2 + 1) << LOG2E) + e];
  int pos = atomicAdd(&cursor[(b << LOG2N) + dst], 1);
  sorted[(b << LOG2E) + pos] = (e << 16) | src;  // eid 15b | src 11b, positive
}

// One thread per (b, node). Single pass over its CSR segment with online softmax.
__global__ void layer_kernel(const float4* __restrict__ h_in, float4* __restrict__ h_out,
                             const int* __restrict__ row_ptr, const int* __restrict__ sorted,
                             const float* __restrict__ edge_time,
                             const float* __restrict__ timestamp,
                             const float* __restrict__ tw,
                             const float* __restrict__ tb,
                             const float* __restrict__ Wq,
                             const float* __restrict__ Wk,
                             const float* __restrict__ Wv,
                             const float* __restrict__ Wo,
                             const float* __restrict__ bo) {
  int g = blockIdx.x * blockDim.x + threadIdx.x;  // B*N exact
  int b = g >> LOG2N, n = g & (N - 1);

  float twf[4], tbf[4], bof[4], wq[16], wof[16], wk[32], wv[32];
#pragma unroll
  for (int j = 0; j < 4; j++) { twf[j] = tw[j]; tbf[j] = tb[j]; bof[j] = bo[j]; }
#pragma unroll
  for (int j = 0; j < 16; j++) { wq[j] = Wq[j]; wof[j] = Wo[j]; }
#pragma unroll
  for (int j = 0; j < 32; j++) { wk[j] = Wk[j]; wv[j] = Wv[j]; }

  float ts = timestamp[b];
  float4 hn = h_in[g];
  // q for this node (it is the dst of all edges in its segment)
  float q0 = hn.x * wq[0] + hn.y * wq[4] + hn.z * wq[8]  + hn.w * wq[12];
  float q1 = hn.x * wq[1] + hn.y * wq[5] + hn.z * wq[9]  + hn.w * wq[13];
  float q2 = hn.x * wq[2] + hn.y * wq[6] + hn.z * wq[10] + hn.w * wq[14];
  float q3 = hn.x * wq[3] + hn.y * wq[7] + hn.z * wq[11] + hn.w * wq[15];

  float m0 = -INFINITY, m1 = -INFINITY;
  float s0 = 0.f, s1 = 0.f, a00 = 0.f, a01 = 0.f, a10 = 0.f, a11 = 0.f;
  int beg = row_ptr[b * (N + 1) + n];
  int end = row_ptr[b * (N + 1) + n + 1];
  for (int i = beg; i < end; ++i) {
    int pk  = sorted[(b << LOG2E) + i];
    int src = pk & 0xFFFF;
    int eid = pk >> 16;
    float dt = ts - edge_time[(b << LOG2E) + eid];
    float4 hs = h_in[(b << LOG2N) + src];
    float msg[8];
    msg[0] = hs.x; msg[1] = hs.y; msg[2] = hs.z; msg[3] = hs.w;
#pragma unroll
    for (int j = 0; j < 4; j++) msg[4 + j] = __cosf(dt * twf[j] + tbf[j]);
    float k0 = 0, k1 = 0, k2 = 0, k3 = 0, v0 = 0, v1 = 0, v2 = 0, v3 = 0;
#pragma unroll
    for (int j = 0; j < 8; j++) {
      k0 += msg[j] * wk[j * 4 + 0]; k1 += msg[j] * wk[j * 4 + 1];
      k2 += msg[j] * wk[j * 4 + 2]; k3 += msg[j] * wk[j * 4 + 3];
      v0 += msg[j] * wv[j * 4 + 0]; v1 += msg[j] * wv[j * 4 + 1];
      v2 += msg[j] * wv[j * 4 + 2]; v3 += msg[j] * wv[j * 4 + 3];
    }
    float l0 = (q0 * k0 + q1 * k1) * 0.70710678118654752f;  // head0: c=0,1
    float l1 = (q2 * k2 + q3 * k3) * 0.70710678118654752f;  // head1: c=2,3
    // online softmax, head 0
    float nm0 = fmaxf(m0, l0);
    float sc0 = __expf(m0 - nm0);  // exp(-inf)=0 on first edge
    float p0  = __expf(l0 - nm0);
    s0 = s0 * sc0 + p0; a00 = a00 * sc0 + p0 * v0; a01 = a01 * sc0 + p0 * v1; m0 = nm0;
    // head 1
    float nm1 = fmaxf(m1, l1);
    float sc1 = __expf(m1 - nm1);
    float p1  = __expf(l1 - nm1);
    s1 = s1 * sc1 + p1; a10 = a10 * sc1 + p1 * v2; a11 = a11 * sc1 + p1 * v3; m1 = nm1;
  }
  float d0 = (s0 == 0.f) ? 1.f : s0;
  float d1 = (s1 == 0.f) ? 1.f : s1;
  float at0 = a00 / d0, at1 = a01 / d0, at2 = a10 / d1, at3 = a11 / d1;
  float o0 = bof[0] + at0 * wof[0] + at1 * wof[4] + at2 * wof[8]  + at3 * wof[12];
  float o1 = bof[1] + at0 * wof[1] + at1 * wof[5] + at2 * wof[9]  + at3 * wof[13];
  float o2 = bof[2] + at0 * wof[2] + at1 * wof[6] + at2 * wof[10] + at3 * wof[14];
  float o3 = bof[3] + at0 * wof[3] + at1 * wof[7] + at2 * wof[11] + at3 * wof[15];
  h_out[g] = make_float4(fmaxf(hn.x + o0, 0.f), fmaxf(hn.y + o1, 0.f),
                         fmaxf(hn.z + o2, 0.f), fmaxf(hn.w + o3, 0.f));
}

__global__ void final_kernel(const float4* __restrict__ h,
                             const int* __restrict__ src_index, const int* __restrict__ dst_index,
                             const float* __restrict__ timestamp,
                             const float* __restrict__ tw,
                             const float* __restrict__ tb,
                             const float* __restrict__ W_lin,
                             const float* __restrict__ b_lin,
                             float* __restrict__ out) {
  int b = threadIdx.x;
  if (b >= B) return;
  float4 sx = h[(b << LOG2N) + src_index[b]];
  float4 dx = h[(b << LOG2N) + dst_index[b]];
  float ts = timestamp[b];
  float f[12];
  f[0] = sx.x; f[1] = sx.y; f[2] = sx.z; f[3] = sx.w;
  f[4] = dx.x; f[5] = dx.y; f[6] = dx.z; f[7] = dx.w;
#pragma unroll
  for (int j = 0; j < 4; j++) f[8 + j] = __cosf(ts * tw[j] + tb[j]);
#pragma unroll
  for (int c = 0; c < 2; c++) {
    float o = b_lin[c];
#pragma unroll
    for (int j = 0; j < 12; j++) o += f[j] * W_lin[j * 2 + c];
    out[b * 2 + c] = o;
  }
}

}  // namespace

extern "C" void kernel_launch(void* const* d_in, const int* in_sizes, int n_in,
                              void* d_out, int out_size, void* d_ws, size_t ws_size,
                              hipStream_t stream) {
  (void)in_sizes; (void)n_in; (void)out_size; (void)ws_size;
  const float* x         = (const float*)d_in[0];
  const int*   edge_idx  = (const int*)d_in[1];
  const float* edge_time = (const float*)d_in[2];
  const float* timestamp = (const float*)d_in[3];
  const int*   src_index = (const int*)d_in[4];
  const int*   dst_index = (const int*)d_in[5];
  const float* time_w    = (const float*)d_in[6];
  const float* time_b    = (const float*)d_in[7];
  const float* Wq        = (const float*)d_in[8];
  const float* Wk        = (const float*)d_in[9];
  const float* Wv        = (const float*)d_in[10];
  const float* Wo        = (const float*)d_in[11];
  const float* bo        = (const float*)d_in[12];
  const float* W_lin     = (const float*)d_in[13];
  const float* b_lin     = (const float*)d_in[14];

  char* ws = (char*)d_ws;
  float4* h0      = (float4*)(ws + OFF_H0);
  float4* h1      = (float4*)(ws + OFF_H1);
  int*    sorted  = (int*)(ws + OFF_SORTED);
  int*    cnt     = (int*)(ws + OFF_CNT);
  int*    cursor  = (int*)(ws + OFF_CUR);
  int*    row_ptr = (int*)(ws + OFF_RP);

  hipMemsetAsync(cnt, 0, (size_t)B * N * sizeof(int), stream);
  hist_kernel<<<(B * E) / 256, 256, 0, stream>>>(edge_idx, cnt);
  scan_kernel<<<B, 256, 0, stream>>>(cnt, row_ptr, cursor);
  scatter_kernel<<<(B * E) / 256, 256, 0, stream>>>(edge_idx, cursor, sorted);

  // layer 0 reads x (already fp32 float4 per node) directly
  layer_kernel<<<(B * N) / 256, 256, 0, stream>>>((const float4*)x, h1, row_ptr, sorted,
                                                  edge_time, timestamp, time_w, time_b,
                                                  Wq + 0 * 16, Wk + 0 * 32, Wv + 0 * 32,
                                                  Wo + 0 * 16, bo + 0 * 4);
  layer_kernel<<<(B * N) / 256, 256, 0, stream>>>(h1, h0, row_ptr, sorted,
                                                  edge_time, timestamp, time_w, time_b,
                                                  Wq + 1 * 16, Wk + 1 * 32, Wv + 1 * 32,
                                                  Wo + 1 * 16, bo + 1 * 4);

  final_kernel<<<1, 128, 0, stream>>>(h0, src_index, dst_index, timestamp, time_w, time_b,
                                      W_lin, b_lin, (float*)d_out);
}

// Round 3
// 447.122 us; speedup vs baseline: 1.6247x; 1.6247x over previous
//
#include <hip/hip_runtime.h>
#include <hip/hip_bf16.h>

namespace {

constexpr int B = 128, N = 2048, E = 32768;
constexpr int LOG2N = 11, LOG2E = 15;

// ws layout (bytes)
constexpr size_t OFF_H0     = 0;                     // B*N float4  = 4 MB
constexpr size_t OFF_H1     = 4u  * 1024 * 1024;     // B*N float4  = 4 MB
constexpr size_t OFF_SORTED = 8u  * 1024 * 1024;     // B*E int     = 16 MB
constexpr size_t OFF_RP     = 24u * 1024 * 1024;     // B*(N+1) int

// One block per batch: LDS counting sort of edges by dst. No global atomics
// (global atomicAdd write-through to HBM cost ~200us/dispatch in R2 —
// WRITE_SIZE 212MB for a 17MB logical output).
__global__ __launch_bounds__(1024) void sort_kernel(const int* __restrict__ edge_index,
                                                    int* __restrict__ sorted,
                                                    int* __restrict__ row_ptr) {
  __shared__ int cnt[N];        // counts -> exclusive offsets -> cursor
  __shared__ int partial[1024];
  int b = blockIdx.x, t = threadIdx.x;
  const int* dst_arr = edge_index + ((size_t)(b * 2 + 1) << LOG2E);
  const int* src_arr = edge_index + ((size_t)(b * 2 + 0) << LOG2E);

  cnt[t] = 0; cnt[t + 1024] = 0;
  __syncthreads();

  // phase 1: histogram via LDS atomics (random dst -> ~2-way bank alias, cheap)
  for (int e = t; e < E; e += 1024) atomicAdd(&cnt[dst_arr[e]], 1);
  __syncthreads();

  // phase 2: block exclusive scan of 2048 counts (2 per thread)
  int base = t * 2;
  int l0 = cnt[base], l1 = cnt[base + 1];
  int sum = l0 + l1;
  partial[t] = sum;
  __syncthreads();
  for (int d = 1; d < 1024; d <<= 1) {
    int v = (t >= d) ? partial[t - d] : 0;
    __syncthreads();
    partial[t] += v;
    __syncthreads();
  }
  int run = partial[t] - sum;  // exclusive offset of this thread's 2-chunk
  __syncthreads();             // all reads of cnt done before overwrite
  cnt[base] = run;
  row_ptr[b * (N + 1) + base] = run;
  int run1 = run + l0;
  cnt[base + 1] = run1;
  row_ptr[b * (N + 1) + base + 1] = run1;
  if (t == 1023) row_ptr[b * (N + 1) + N] = E;
  __syncthreads();

  // phase 3: scatter with LDS cursor
  int* out = sorted + ((size_t)b << LOG2E);
  for (int e = t; e < E; e += 1024) {
    int dst = dst_arr[e];
    int src = src_arr[e];
    int pos = atomicAdd(&cnt[dst], 1);
    out[pos] = (e << 16) | src;  // eid 15b | src 11b
  }
}

// One thread per (b, node). Single pass over its CSR segment with online softmax.
__global__ void layer_kernel(const float4* __restrict__ h_in, float4* __restrict__ h_out,
                             const int* __restrict__ row_ptr, const int* __restrict__ sorted,
                             const float* __restrict__ edge_time,
                             const float* __restrict__ timestamp,
                             const float* __restrict__ tw,
                             const float* __restrict__ tb,
                             const float* __restrict__ Wq,
                             const float* __restrict__ Wk,
                             const float* __restrict__ Wv,
                             const float* __restrict__ Wo,
                             const float* __restrict__ bo) {
  int g = blockIdx.x * blockDim.x + threadIdx.x;  // B*N exact
  int b = g >> LOG2N, n = g & (N - 1);

  float twf[4], tbf[4], bof[4], wq[16], wof[16], wk[32], wv[32];
#pragma unroll
  for (int j = 0; j < 4; j++) { twf[j] = tw[j]; tbf[j] = tb[j]; bof[j] = bo[j]; }
#pragma unroll
  for (int j = 0; j < 16; j++) { wq[j] = Wq[j]; wof[j] = Wo[j]; }
#pragma unroll
  for (int j = 0; j < 32; j++) { wk[j] = Wk[j]; wv[j] = Wv[j]; }

  float ts = timestamp[b];
  float4 hn = h_in[g];
  float q0 = hn.x * wq[0] + hn.y * wq[4] + hn.z * wq[8]  + hn.w * wq[12];
  float q1 = hn.x * wq[1] + hn.y * wq[5] + hn.z * wq[9]  + hn.w * wq[13];
  float q2 = hn.x * wq[2] + hn.y * wq[6] + hn.z * wq[10] + hn.w * wq[14];
  float q3 = hn.x * wq[3] + hn.y * wq[7] + hn.z * wq[11] + hn.w * wq[15];

  float m0 = -INFINITY, m1 = -INFINITY;
  float s0 = 0.f, s1 = 0.f, a00 = 0.f, a01 = 0.f, a10 = 0.f, a11 = 0.f;
  int beg = row_ptr[b * (N + 1) + n];
  int end = row_ptr[b * (N + 1) + n + 1];
  for (int i = beg; i < end; ++i) {
    int pk  = sorted[(b << LOG2E) + i];
    int src = pk & 0xFFFF;
    int eid = pk >> 16;
    float dt = ts - edge_time[(b << LOG2E) + eid];
    float4 hs = h_in[(b << LOG2N) + src];
    float msg[8];
    msg[0] = hs.x; msg[1] = hs.y; msg[2] = hs.z; msg[3] = hs.w;
#pragma unroll
    for (int j = 0; j < 4; j++) msg[4 + j] = __cosf(dt * twf[j] + tbf[j]);
    float k0 = 0, k1 = 0, k2 = 0, k3 = 0, v0 = 0, v1 = 0, v2 = 0, v3 = 0;
#pragma unroll
    for (int j = 0; j < 8; j++) {
      k0 += msg[j] * wk[j * 4 + 0]; k1 += msg[j] * wk[j * 4 + 1];
      k2 += msg[j] * wk[j * 4 + 2]; k3 += msg[j] * wk[j * 4 + 3];
      v0 += msg[j] * wv[j * 4 + 0]; v1 += msg[j] * wv[j * 4 + 1];
      v2 += msg[j] * wv[j * 4 + 2]; v3 += msg[j] * wv[j * 4 + 3];
    }
    float l0 = (q0 * k0 + q1 * k1) * 0.70710678118654752f;  // head0: c=0,1
    float l1 = (q2 * k2 + q3 * k3) * 0.70710678118654752f;  // head1: c=2,3
    float nm0 = fmaxf(m0, l0);
    float sc0 = __expf(m0 - nm0);
    float p0  = __expf(l0 - nm0);
    s0 = s0 * sc0 + p0; a00 = a00 * sc0 + p0 * v0; a01 = a01 * sc0 + p0 * v1; m0 = nm0;
    float nm1 = fmaxf(m1, l1);
    float sc1 = __expf(m1 - nm1);
    float p1  = __expf(l1 - nm1);
    s1 = s1 * sc1 + p1; a10 = a10 * sc1 + p1 * v2; a11 = a11 * sc1 + p1 * v3; m1 = nm1;
  }
  float d0 = (s0 == 0.f) ? 1.f : s0;
  float d1 = (s1 == 0.f) ? 1.f : s1;
  float at0 = a00 / d0, at1 = a01 / d0, at2 = a10 / d1, at3 = a11 / d1;
  float o0 = bof[0] + at0 * wof[0] + at1 * wof[4] + at2 * wof[8]  + at3 * wof[12];
  float o1 = bof[1] + at0 * wof[1] + at1 * wof[5] + at2 * wof[9]  + at3 * wof[13];
  float o2 = bof[2] + at0 * wof[2] + at1 * wof[6] + at2 * wof[10] + at3 * wof[14];
  float o3 = bof[3] + at0 * wof[3] + at1 * wof[7] + at2 * wof[11] + at3 * wof[15];
  h_out[g] = make_float4(fmaxf(hn.x + o0, 0.f), fmaxf(hn.y + o1, 0.f),
                         fmaxf(hn.z + o2, 0.f), fmaxf(hn.w + o3, 0.f));
}

__global__ void final_kernel(const float4* __restrict__ h,
                             const int* __restrict__ src_index, const int* __restrict__ dst_index,
                             const float* __restrict__ timestamp,
                             const float* __restrict__ tw,
                             const float* __restrict__ tb,
                             const float* __restrict__ W_lin,
                             const float* __restrict__ b_lin,
                             float* __restrict__ out) {
  int b = threadIdx.x;
  if (b >= B) return;
  float4 sx = h[(b << LOG2N) + src_index[b]];
  float4 dx = h[(b << LOG2N) + dst_index[b]];
  float ts = timestamp[b];
  float f[12];
  f[0] = sx.x; f[1] = sx.y; f[2] = sx.z; f[3] = sx.w;
  f[4] = dx.x; f[5] = dx.y; f[6] = dx.z; f[7] = dx.w;
#pragma unroll
  for (int j = 0; j < 4; j++) f[8 + j] = __cosf(ts * tw[j] + tb[j]);
#pragma unroll
  for (int c = 0; c < 2; c++) {
    float o = b_lin[c];
#pragma unroll
    for (int j = 0; j < 12; j++) o += f[j] * W_lin[j * 2 + c];
    out[b * 2 + c] = o;
  }
}

}  // namespace

extern "C" void kernel_launch(void* const* d_in, const int* in_sizes, int n_in,
                              void* d_out, int out_size, void* d_ws, size_t ws_size,
                              hipStream_t stream) {
  (void)in_sizes; (void)n_in; (void)out_size; (void)ws_size;
  const float* x         = (const float*)d_in[0];
  const int*   edge_idx  = (const int*)d_in[1];
  const float* edge_time = (const float*)d_in[2];
  const float* timestamp = (const float*)d_in[3];
  const int*   src_index = (const int*)d_in[4];
  const int*   dst_index = (const int*)d_in[5];
  const float* time_w    = (const float*)d_in[6];
  const float* time_b    = (const float*)d_in[7];
  const float* Wq        = (const float*)d_in[8];
  const float* Wk        = (const float*)d_in[9];
  const float* Wv        = (const float*)d_in[10];
  const float* Wo        = (const float*)d_in[11];
  const float* bo        = (const float*)d_in[12];
  const float* W_lin     = (const float*)d_in[13];
  const float* b_lin     = (const float*)d_in[14];

  char* ws = (char*)d_ws;
  float4* h0      = (float4*)(ws + OFF_H0);
  float4* h1      = (float4*)(ws + OFF_H1);
  int*    sorted  = (int*)(ws + OFF_SORTED);
  int*    row_ptr = (int*)(ws + OFF_RP);

  sort_kernel<<<B, 1024, 0, stream>>>(edge_idx, sorted, row_ptr);

  // layer 0 reads x (already fp32 float4 per node) directly
  layer_kernel<<<(B * N) / 256, 256, 0, stream>>>((const float4*)x, h1, row_ptr, sorted,
                                                  edge_time, timestamp, time_w, time_b,
                                                  Wq + 0 * 16, Wk + 0 * 32, Wv + 0 * 32,
                                                  Wo + 0 * 16, bo + 0 * 4);
  layer_kernel<<<(B * N) / 256, 256, 0, stream>>>(h1, h0, row_ptr, sorted,
                                                  edge_time, timestamp, time_w, time_b,
                                                  Wq + 1 * 16, Wk + 1 * 32, Wv + 1 * 32,
                                                  Wo + 1 * 16, bo + 1 * 4);

  final_kernel<<<1, 128, 0, stream>>>(h0, src_index, dst_index, timestamp, time_w, time_b,
                                      W_lin, b_lin, (float*)d_out);
}

// Round 4
// 273.576 us; speedup vs baseline: 2.6553x; 1.6344x over previous
//
#include <hip/hip_runtime.h>

namespace {

constexpr int B = 128, N = 2048, E = 32768;
constexpr int LOG2N = 11, LOG2E = 15;
constexpr int HALF_E = E / 2;

// ws layout (bytes)
constexpr size_t OFF_H0   = 0;                      // B*N float4 = 4 MB
constexpr size_t OFF_H1   = 4u  * 1024 * 1024;      // B*N float4 = 4 MB
constexpr size_t OFF_S8   = 8u  * 1024 * 1024;      // B*E int2   = 32 MB
constexpr size_t OFF_RP   = 40u * 1024 * 1024;      // B*(N+1) int ~1 MB
constexpr size_t OFF_HIST = 42u * 1024 * 1024;      // B*2*N int  = 2 MB
constexpr size_t OFF_CURB = 44u * 1024 * 1024;      // B*2*N int  = 2 MB

// ---- sort phase A: per-half-batch histogram (LDS atomics only) ----
__global__ __launch_bounds__(1024) void hist_kernel(const int* __restrict__ edge_index,
                                                    int* __restrict__ hist_part) {
  __shared__ int cnt[N];
  int blk = blockIdx.x, b = blk >> 1, half = blk & 1, t = threadIdx.x;
  cnt[t] = 0; cnt[t + 1024] = 0;
  __syncthreads();
  const int* dst_arr = edge_index + (((size_t)(b * 2 + 1)) << LOG2E) + half * HALF_E;
  for (int e = t; e < HALF_E; e += 1024) atomicAdd(&cnt[dst_arr[e]], 1);
  __syncthreads();
  size_t base = ((size_t)blk) << LOG2N;
  hist_part[base + t] = cnt[t];
  hist_part[base + t + 1024] = cnt[t + 1024];
}

// ---- sort phase B: per-batch exclusive scan -> row_ptr + per-half cursor bases ----
__global__ __launch_bounds__(1024) void scan_kernel(const int* __restrict__ hist_part,
                                                    int* __restrict__ row_ptr,
                                                    int* __restrict__ cur_base) {
  __shared__ int partial[1024];
  int b = blockIdx.x, t = threadIdx.x;
  const int2* hp0 = (const int2*)(hist_part + (((size_t)(b * 2 + 0)) << LOG2N));
  const int2* hp1 = (const int2*)(hist_part + (((size_t)(b * 2 + 1)) << LOG2N));
  int2 A = hp0[t];  // first-half counts for nodes 2t, 2t+1
  int2 Bc = hp1[t]; // second-half counts
  int tot0 = A.x + Bc.x, tot1 = A.y + Bc.y;
  int sum = tot0 + tot1;
  partial[t] = sum;
  __syncthreads();
  for (int d = 1; d < 1024; d <<= 1) {
    int v = (t >= d) ? partial[t - d] : 0;
    __syncthreads();
    partial[t] += v;
    __syncthreads();
  }
  int run = partial[t] - sum;  // exclusive offset of node 2t
  int i0 = 2 * t, i1 = 2 * t + 1;
  int run2 = run + tot0;       // exclusive offset of node 2t+1
  row_ptr[b * (N + 1) + i0] = run;
  row_ptr[b * (N + 1) + i1] = run2;
  if (t == 1023) row_ptr[b * (N + 1) + N] = E;
  int* cb0 = cur_base + (((size_t)(b * 2 + 0)) << LOG2N);
  int* cb1 = cur_base + (((size_t)(b * 2 + 1)) << LOG2N);
  cb0[i0] = run;        cb1[i0] = run + A.x;
  cb0[i1] = run2;       cb1[i1] = run2 + A.y;
}

// ---- sort phase C: scatter (src, dt) records with LDS cursors ----
__global__ __launch_bounds__(1024) void scatter_kernel(const int* __restrict__ edge_index,
                                                       const float* __restrict__ edge_time,
                                                       const float* __restrict__ timestamp,
                                                       const int* __restrict__ cur_base,
                                                       int2* __restrict__ sorted8) {
  __shared__ int cnt[N];
  int blk = blockIdx.x, b = blk >> 1, half = blk & 1, t = threadIdx.x;
  size_t cbase = ((size_t)blk) << LOG2N;
  cnt[t] = cur_base[cbase + t];
  cnt[t + 1024] = cur_base[cbase + t + 1024];
  __syncthreads();
  float ts = timestamp[b];
  const int* src_arr = edge_index + (((size_t)(b * 2 + 0)) << LOG2E) + half * HALF_E;
  const int* dst_arr = edge_index + (((size_t)(b * 2 + 1)) << LOG2E) + half * HALF_E;
  const float* et    = edge_time + (((size_t)b) << LOG2E) + half * HALF_E;
  int2* out = sorted8 + (((size_t)b) << LOG2E);
  for (int e = t; e < HALF_E; e += 1024) {
    int dst = dst_arr[e];
    int src = src_arr[e];
    float dt = ts - et[e];
    int pos = atomicAdd(&cnt[dst], 1);
    out[pos] = make_int2(src, __float_as_int(dt));
  }
}

// ---- layer: 2 blocks per batch, h staged in LDS, sequential edge records ----
__global__ __launch_bounds__(1024) void layer_kernel(const float4* __restrict__ h_in,
                                                     float4* __restrict__ h_out,
                                                     const int* __restrict__ row_ptr,
                                                     const int2* __restrict__ sorted8,
                                                     const float* __restrict__ tw,
                                                     const float* __restrict__ tb,
                                                     const float* __restrict__ Wq,
                                                     const float* __restrict__ Wk,
                                                     const float* __restrict__ Wv,
                                                     const float* __restrict__ Wo,
                                                     const float* __restrict__ bo) {
  __shared__ float4 lh[N];  // 32 KB: full batch h slice
  int blk = blockIdx.x, b = blk >> 1, half = blk & 1, t = threadIdx.x;

  const float4* hb = h_in + (((size_t)b) << LOG2N);
  lh[t] = hb[t];
  lh[t + 1024] = hb[t + 1024];

  float twf[4], tbf[4], bof[4], wq[16], wof[16], wk[32], wv[32];
#pragma unroll
  for (int j = 0; j < 4; j++) { twf[j] = tw[j]; tbf[j] = tb[j]; bof[j] = bo[j]; }
#pragma unroll
  for (int j = 0; j < 16; j++) { wq[j] = Wq[j]; wof[j] = Wo[j]; }
#pragma unroll
  for (int j = 0; j < 32; j++) { wk[j] = Wk[j]; wv[j] = Wv[j]; }
  __syncthreads();

  int n = half * 1024 + t;
  float4 hn = lh[n];
  float q0 = hn.x * wq[0] + hn.y * wq[4] + hn.z * wq[8]  + hn.w * wq[12];
  float q1 = hn.x * wq[1] + hn.y * wq[5] + hn.z * wq[9]  + hn.w * wq[13];
  float q2 = hn.x * wq[2] + hn.y * wq[6] + hn.z * wq[10] + hn.w * wq[14];
  float q3 = hn.x * wq[3] + hn.y * wq[7] + hn.z * wq[11] + hn.w * wq[15];

  float m0 = -INFINITY, m1 = -INFINITY;
  float s0 = 0.f, s1 = 0.f, a00 = 0.f, a01 = 0.f, a10 = 0.f, a11 = 0.f;
  int beg = row_ptr[b * (N + 1) + n];
  int end = row_ptr[b * (N + 1) + n + 1];
  const int2* srt = sorted8 + (((size_t)b) << LOG2E);
  for (int i = beg; i < end; ++i) {
    int2 rec = srt[i];
    float dt = __int_as_float(rec.y);
    float4 hs = lh[rec.x];
    float msg[8];
    msg[0] = hs.x; msg[1] = hs.y; msg[2] = hs.z; msg[3] = hs.w;
#pragma unroll
    for (int j = 0; j < 4; j++) msg[4 + j] = __cosf(dt * twf[j] + tbf[j]);
    float k0 = 0, k1 = 0, k2 = 0, k3 = 0, v0 = 0, v1 = 0, v2 = 0, v3 = 0;
#pragma unroll
    for (int j = 0; j < 8; j++) {
      k0 += msg[j] * wk[j * 4 + 0]; k1 += msg[j] * wk[j * 4 + 1];
      k2 += msg[j] * wk[j * 4 + 2]; k3 += msg[j] * wk[j * 4 + 3];
      v0 += msg[j] * wv[j * 4 + 0]; v1 += msg[j] * wv[j * 4 + 1];
      v2 += msg[j] * wv[j * 4 + 2]; v3 += msg[j] * wv[j * 4 + 3];
    }
    float l0 = (q0 * k0 + q1 * k1) * 0.70710678118654752f;  // head0: c=0,1
    float l1 = (q2 * k2 + q3 * k3) * 0.70710678118654752f;  // head1: c=2,3
    float nm0 = fmaxf(m0, l0);
    float sc0 = __expf(m0 - nm0);
    float p0  = __expf(l0 - nm0);
    s0 = s0 * sc0 + p0; a00 = a00 * sc0 + p0 * v0; a01 = a01 * sc0 + p0 * v1; m0 = nm0;
    float nm1 = fmaxf(m1, l1);
    float sc1 = __expf(m1 - nm1);
    float p1  = __expf(l1 - nm1);
    s1 = s1 * sc1 + p1; a10 = a10 * sc1 + p1 * v2; a11 = a11 * sc1 + p1 * v3; m1 = nm1;
  }
  float d0 = (s0 == 0.f) ? 1.f : s0;
  float d1 = (s1 == 0.f) ? 1.f : s1;
  float at0 = a00 / d0, at1 = a01 / d0, at2 = a10 / d1, at3 = a11 / d1;
  float o0 = bof[0] + at0 * wof[0] + at1 * wof[4] + at2 * wof[8]  + at3 * wof[12];
  float o1 = bof[1] + at0 * wof[1] + at1 * wof[5] + at2 * wof[9]  + at3 * wof[13];
  float o2 = bof[2] + at0 * wof[2] + at1 * wof[6] + at2 * wof[10] + at3 * wof[14];
  float o3 = bof[3] + at0 * wof[3] + at1 * wof[7] + at2 * wof[11] + at3 * wof[15];
  h_out[(((size_t)b) << LOG2N) + n] =
      make_float4(fmaxf(hn.x + o0, 0.f), fmaxf(hn.y + o1, 0.f),
                  fmaxf(hn.z + o2, 0.f), fmaxf(hn.w + o3, 0.f));
}

__global__ void final_kernel(const float4* __restrict__ h,
                             const int* __restrict__ src_index, const int* __restrict__ dst_index,
                             const float* __restrict__ timestamp,
                             const float* __restrict__ tw,
                             const float* __restrict__ tb,
                             const float* __restrict__ W_lin,
                             const float* __restrict__ b_lin,
                             float* __restrict__ out) {
  int b = threadIdx.x;
  if (b >= B) return;
  float4 sx = h[(((size_t)b) << LOG2N) + src_index[b]];
  float4 dx = h[(((size_t)b) << LOG2N) + dst_index[b]];
  float ts = timestamp[b];
  float f[12];
  f[0] = sx.x; f[1] = sx.y; f[2] = sx.z; f[3] = sx.w;
  f[4] = dx.x; f[5] = dx.y; f[6] = dx.z; f[7] = dx.w;
#pragma unroll
  for (int j = 0; j < 4; j++) f[8 + j] = __cosf(ts * tw[j] + tb[j]);
#pragma unroll
  for (int c = 0; c < 2; c++) {
    float o = b_lin[c];
#pragma unroll
    for (int j = 0; j < 12; j++) o += f[j] * W_lin[j * 2 + c];
    out[b * 2 + c] = o;
  }
}

}  // namespace

extern "C" void kernel_launch(void* const* d_in, const int* in_sizes, int n_in,
                              void* d_out, int out_size, void* d_ws, size_t ws_size,
                              hipStream_t stream) {
  (void)in_sizes; (void)n_in; (void)out_size; (void)ws_size;
  const float* x         = (const float*)d_in[0];
  const int*   edge_idx  = (const int*)d_in[1];
  const float* edge_time = (const float*)d_in[2];
  const float* timestamp = (const float*)d_in[3];
  const int*   src_index = (const int*)d_in[4];
  const int*   dst_index = (const int*)d_in[5];
  const float* time_w    = (const float*)d_in[6];
  const float* time_b    = (const float*)d_in[7];
  const float* Wq        = (const float*)d_in[8];
  const float* Wk        = (const float*)d_in[9];
  const float* Wv        = (const float*)d_in[10];
  const float* Wo        = (const float*)d_in[11];
  const float* bo        = (const float*)d_in[12];
  const float* W_lin     = (const float*)d_in[13];
  const float* b_lin     = (const float*)d_in[14];

  char* ws = (char*)d_ws;
  float4* h0       = (float4*)(ws + OFF_H0);
  float4* h1       = (float4*)(ws + OFF_H1);
  int2*   sorted8  = (int2*)(ws + OFF_S8);
  int*    row_ptr  = (int*)(ws + OFF_RP);
  int*    hist     = (int*)(ws + OFF_HIST);
  int*    cur_base = (int*)(ws + OFF_CURB);

  hist_kernel<<<2 * B, 1024, 0, stream>>>(edge_idx, hist);
  scan_kernel<<<B, 1024, 0, stream>>>(hist, row_ptr, cur_base);
  scatter_kernel<<<2 * B, 1024, 0, stream>>>(edge_idx, edge_time, timestamp, cur_base, sorted8);

  layer_kernel<<<2 * B, 1024, 0, stream>>>((const float4*)x, h1, row_ptr, sorted8,
                                           time_w, time_b,
                                           Wq + 0 * 16, Wk + 0 * 32, Wv + 0 * 32,
                                           Wo + 0 * 16, bo + 0 * 4);
  layer_kernel<<<2 * B, 1024, 0, stream>>>(h1, h0, row_ptr, sorted8,
                                           time_w, time_b,
                                           Wq + 1 * 16, Wk + 1 * 32, Wv + 1 * 32,
                                           Wo + 1 * 16, bo + 1 * 4);

  final_kernel<<<1, 128, 0, stream>>>(h0, src_index, dst_index, timestamp, time_w, time_b,
                                      W_lin, b_lin, (float*)d_out);
}